// Round 2
// baseline (9039.409 us; speedup 1.0000x reference)
//
#include <hip/hip_runtime.h>
#include <math.h>

// Problem dims
#define SSRC 50
#define NBATCH 64
#define EDIM 300
#define HDIM 512
#define G4H 2048
#define VTGT 10000
#define TSTEPS 49

// ---------------------------------------------------------------------------
// Generic tiled fp32 GEMM: C[m][n] = sum_k A[m][k]*B[n][k] + bias[n]
// A row m optionally gathered: row = aidx[m] (embedding fusion).
// 128x128 tile, BK=8, 256 threads, 8x8 per thread.
// ---------------------------------------------------------------------------
__global__ __launch_bounds__(256)
void gemm_bias_kernel(const float* __restrict__ A, const int* __restrict__ aidx, int lda,
                      const float* __restrict__ B, int ldb,
                      const float* __restrict__ bias,
                      float* __restrict__ C, int ldc,
                      int M, int N, int K)
{
    __shared__ float As[8][128];
    __shared__ float Bs[8][128];
    const int tid = threadIdx.x;
    const int bm = blockIdx.y * 128;
    const int bn = blockIdx.x * 128;
    const int tx = tid & 15;
    const int ty = tid >> 4;

    float acc[8][8];
#pragma unroll
    for (int i = 0; i < 8; ++i)
#pragma unroll
        for (int j = 0; j < 8; ++j) acc[i][j] = 0.f;

    for (int k0 = 0; k0 < K; k0 += 8) {
#pragma unroll
        for (int i = 0; i < 4; ++i) {
            int idx = tid + i * 256;       // 0..1023
            int r  = idx >> 3;             // 0..127
            int kk = idx & 7;
            int gk = k0 + kk;
            float va = 0.f;
            int gm = bm + r;
            if (gm < M && gk < K) {
                long arow = aidx ? (long)aidx[gm] : (long)gm;
                va = A[arow * (long)lda + gk];
            }
            As[kk][r] = va;
            float vb = 0.f;
            int gn = bn + r;
            if (gn < N && gk < K) vb = B[(long)gn * ldb + gk];
            Bs[kk][r] = vb;
        }
        __syncthreads();
#pragma unroll
        for (int kk = 0; kk < 8; ++kk) {
            const float4 a0 = *reinterpret_cast<const float4*>(&As[kk][ty * 8]);
            const float4 a1 = *reinterpret_cast<const float4*>(&As[kk][ty * 8 + 4]);
            const float4 b0 = *reinterpret_cast<const float4*>(&Bs[kk][tx * 8]);
            const float4 b1 = *reinterpret_cast<const float4*>(&Bs[kk][tx * 8 + 4]);
            const float a[8] = {a0.x, a0.y, a0.z, a0.w, a1.x, a1.y, a1.z, a1.w};
            const float b[8] = {b0.x, b0.y, b0.z, b0.w, b1.x, b1.y, b1.z, b1.w};
#pragma unroll
            for (int i = 0; i < 8; ++i)
#pragma unroll
                for (int j = 0; j < 8; ++j)
                    acc[i][j] = fmaf(a[i], b[j], acc[i][j]);
        }
        __syncthreads();
    }

#pragma unroll
    for (int i = 0; i < 8; ++i) {
        int m = bm + ty * 8 + i;
        if (m >= M) continue;
#pragma unroll
        for (int j = 0; j < 8; ++j) {
            int n = bn + tx * 8 + j;
            if (n >= N) continue;
            float v = acc[i][j];
            if (bias) v += bias[n];
            C[(long)m * ldc + n] = v;
        }
    }
}

// ---------------------------------------------------------------------------
// One recurrent LSTM step (gates GEMM vs. small-M recurrent inputs + pointwise).
// gates[n][j] = X[n][j] + sum_l A1[n][l]*W1[j][l] (+ sum_l A2[n][l]*W2[j][l])
// then i,f,g,o split (chunks of 512), LSTM update, h stored to h_out (+h_store).
// Grid: 256 blocks per set (k-range of 2 per block, 8 gate rows). Two sets
// (fwd+bwd encoder) fused into one launch when grid==512.
// ---------------------------------------------------------------------------
struct LstmSet {
    const float* X;                 // 64 x 2048 (input contribution + bias)
    const float* A1; const float* W1; int K1; int ldw1;
    const float* A2; const float* W2; int K2; int ldw2;   // A2 may be null
    const float* c_in;
    float* h_out; float* c_out; float* h_store;           // h_store may be null
};

__global__ __launch_bounds__(256)
void lstm_step_kernel(LstmSet s0, LstmSet s1)
{
    __shared__ float Wl[8 * 1536];
    __shared__ float gbuf[64 * 8];
    const LstmSet s = (blockIdx.x >> 8) ? s1 : s0;
    const int b = blockIdx.x & 255;
    const int tid = threadIdx.x;
    const int k0 = b * 2;
    const int KT = s.K1 + s.K2;

    // stage the 8 weight rows (i = kk*4 + g  ->  j = g*512 + k0 + kk)
    for (int idx = tid; idx < 8 * KT; idx += 256) {
        int i = idx / KT;
        int l = idx - i * KT;
        int kk = i >> 2, g = i & 3;
        int j = g * HDIM + k0 + kk;
        float v;
        if (l < s.K1) v = s.W1[(long)j * s.ldw1 + l];
        else          v = s.W2[(long)j * s.ldw2 + (l - s.K1)];
        Wl[i * KT + l] = v;
    }
    __syncthreads();

    const int n = tid & 63;
    const int p = tid >> 6;                 // gate index g
    float acc0 = s.X[n * G4H + p * HDIM + k0];      // kk = 0
    float acc1 = s.X[n * G4H + p * HDIM + k0 + 1];  // kk = 1
    const float* w0 = &Wl[p * KT];
    const float* w1 = &Wl[(p + 4) * KT];
    {
        const float4* a4  = reinterpret_cast<const float4*>(s.A1 + (long)n * s.K1);
        const float4* w04 = reinterpret_cast<const float4*>(w0);
        const float4* w14 = reinterpret_cast<const float4*>(w1);
        const int n4 = s.K1 >> 2;
        for (int l = 0; l < n4; ++l) {
            float4 av = a4[l], u = w04[l], v = w14[l];
            acc0 = fmaf(av.x, u.x, fmaf(av.y, u.y, fmaf(av.z, u.z, fmaf(av.w, u.w, acc0))));
            acc1 = fmaf(av.x, v.x, fmaf(av.y, v.y, fmaf(av.z, v.z, fmaf(av.w, v.w, acc1))));
        }
    }
    if (s.A2) {
        const float4* a4  = reinterpret_cast<const float4*>(s.A2 + (long)n * s.K2);
        const float4* w04 = reinterpret_cast<const float4*>(w0 + s.K1);
        const float4* w14 = reinterpret_cast<const float4*>(w1 + s.K1);
        const int n4 = s.K2 >> 2;
        for (int l = 0; l < n4; ++l) {
            float4 av = a4[l], u = w04[l], v = w14[l];
            acc0 = fmaf(av.x, u.x, fmaf(av.y, u.y, fmaf(av.z, u.z, fmaf(av.w, u.w, acc0))));
            acc1 = fmaf(av.x, v.x, fmaf(av.y, v.y, fmaf(av.z, v.z, fmaf(av.w, v.w, acc1))));
        }
    }
    gbuf[n * 8 + p]     = acc0;   // i = 0*4 + p
    gbuf[n * 8 + p + 4] = acc1;   // i = 1*4 + p
    __syncthreads();

    if (tid < 128) {
        const int n2 = tid & 63;
        const int kk = tid >> 6;
        const int k = k0 + kk;
        const float gi = gbuf[n2 * 8 + kk * 4 + 0];
        const float gf = gbuf[n2 * 8 + kk * 4 + 1];
        const float gg = gbuf[n2 * 8 + kk * 4 + 2];
        const float go = gbuf[n2 * 8 + kk * 4 + 3];
        const float cold = s.c_in[n2 * HDIM + k];
        const float si = 1.f / (1.f + __expf(-gi));
        const float sf = 1.f / (1.f + __expf(-gf));
        const float so = 1.f / (1.f + __expf(-go));
        const float tg = tanhf(gg);
        const float cn = sf * cold + si * tg;
        const float hn = so * tanhf(cn);
        s.c_out[n2 * HDIM + k] = cn;
        s.h_out[n2 * HDIM + k] = hn;
        if (s.h_store) s.h_store[n2 * HDIM + k] = hn;
    }
}

// ---------------------------------------------------------------------------
// Step-invariant attention key term: ee[s][n] = states[s][n]·We + energy_b
// states = [out_f | out_b_rev]. One wave per (s,n).
// ---------------------------------------------------------------------------
__global__ __launch_bounds__(64)
void ee_kernel(const float* __restrict__ out_f, const float* __restrict__ out_b,
               const float* __restrict__ We, const float* __restrict__ energy_b,
               float* __restrict__ ee)
{
    const int sn = blockIdx.x;        // s*64 + n
    const int lane = threadIdx.x;
    const float* f = out_f + (long)sn * HDIM;
    const float* bb = out_b + (long)sn * HDIM;
    float p = 0.f;
    for (int l = lane; l < HDIM; l += 64)
        p = fmaf(f[l], We[l], fmaf(bb[l], We[HDIM + l], p));
#pragma unroll
    for (int off = 32; off > 0; off >>= 1) p += __shfl_down(p, off);
    if (lane == 0) ee[sn] = p + energy_b[0];
}

// concat two 64x512 buffers -> 64 x 1024
__global__ __launch_bounds__(256)
void hcat_kernel(const float* __restrict__ a, const float* __restrict__ b,
                 float* __restrict__ cat)
{
    const int n = blockIdx.x;
    for (int l = threadIdx.x; l < 2 * HDIM; l += 256)
        cat[n * 2 * HDIM + l] = (l < HDIM) ? a[n * HDIM + l] : b[n * HDIM + l - HDIM];
}

// ---------------------------------------------------------------------------
// Attention for one decoder step: energy -> relu -> softmax(s) -> context.
// One block per batch element n.
// ---------------------------------------------------------------------------
__global__ __launch_bounds__(256)
void attn_kernel(const float* __restrict__ h,      // 64 x 512
                 const float* __restrict__ Wh,     // energy_W[0:512]
                 const float* __restrict__ ee,     // 50 x 64 (incl. bias)
                 const float* __restrict__ out_f,  // 50 x 64 x 512
                 const float* __restrict__ out_b,  // pre-reversed
                 float* __restrict__ ctx)          // 64 x 1024
{
    const int n = blockIdx.x;
    const int tid = threadIdx.x;
    __shared__ float red[256];
    __shared__ float attn[SSRC];

    float p = 0.f;
    for (int l = tid; l < HDIM; l += 256) p = fmaf(h[n * HDIM + l], Wh[l], p);
    red[tid] = p;
    __syncthreads();
    for (int off = 128; off > 0; off >>= 1) {
        if (tid < off) red[tid] += red[tid + off];
        __syncthreads();
    }
    const float hdot = red[0];

    if (tid < SSRC) {
        float e = hdot + ee[tid * NBATCH + n];
        attn[tid] = e > 0.f ? e : 0.f;
    }
    __syncthreads();
    if (tid == 0) {
        float m = 0.f;
        for (int s2 = 0; s2 < SSRC; ++s2) m = fmaxf(m, attn[s2]);
        float sum = 0.f;
        for (int s2 = 0; s2 < SSRC; ++s2) { float ex = __expf(attn[s2] - m); attn[s2] = ex; sum += ex; }
        float inv = 1.f / sum;
        for (int s2 = 0; s2 < SSRC; ++s2) attn[s2] *= inv;
    }
    __syncthreads();

    for (int l = tid; l < 2 * HDIM; l += 256) {
        const float* src = (l < HDIM) ? (out_f + (long)n * HDIM + l)
                                      : (out_b + (long)n * HDIM + (l - HDIM));
        float acc = 0.f;
        for (int s2 = 0; s2 < SSRC; ++s2)
            acc = fmaf(attn[s2], src[(long)s2 * NBATCH * HDIM], acc);
        ctx[n * 2 * HDIM + l] = acc;
    }
}

// ---------------------------------------------------------------------------
extern "C" void kernel_launch(void* const* d_in, const int* in_sizes, int n_in,
                              void* d_out, int out_size, void* d_ws, size_t ws_size,
                              hipStream_t stream)
{
    const int*   source    = (const int*)  d_in[0];
    const int*   target    = (const int*)  d_in[1];
    const float* enc_emb   = (const float*)d_in[2];
    const float* enc_Wih_f = (const float*)d_in[3];
    const float* enc_Whh_f = (const float*)d_in[4];
    const float* enc_b_f   = (const float*)d_in[5];
    const float* enc_Wih_b = (const float*)d_in[6];
    const float* enc_Whh_b = (const float*)d_in[7];
    const float* enc_b_b   = (const float*)d_in[8];
    const float* fc_hid_W  = (const float*)d_in[9];
    const float* fc_hid_b  = (const float*)d_in[10];
    const float* fc_cell_W = (const float*)d_in[11];
    const float* fc_cell_b = (const float*)d_in[12];
    const float* dec_emb   = (const float*)d_in[13];
    const float* dec_Wih   = (const float*)d_in[14];
    const float* dec_Whh   = (const float*)d_in[15];
    const float* dec_b     = (const float*)d_in[16];
    const float* energy_W  = (const float*)d_in[17];
    const float* energy_b  = (const float*)d_in[18];
    const float* fc_W      = (const float*)d_in[19];
    const float* fc_b      = (const float*)d_in[20];
    float* out = (float*)d_out;

    float* w = (float*)d_ws;
    size_t o = 0;
    auto alloc = [&](size_t nf) { float* p = w + o; o += nf; return p; };
    const int HS = NBATCH * HDIM;                  // 32768
    float* Xf    = alloc((size_t)SSRC * NBATCH * G4H);   // 6.55M
    float* Xb    = alloc((size_t)SSRC * NBATCH * G4H);
    float* out_f = alloc((size_t)SSRC * HS);
    float* out_b = alloc((size_t)SSRC * HS);             // stored pre-reversed
    float* Hs    = alloc((size_t)TSTEPS * HS);
    float* st    = alloc((size_t)8 * HS);   // hf0 cf0 hb0 cb0 | hf1 cf1 hb1 cb1
    float* dst   = alloc((size_t)4 * HS);   // dh0 dc0 dh1 dc1
    float* hcat  = alloc((size_t)NBATCH * 2 * HDIM);
    float* ccat  = alloc((size_t)NBATCH * 2 * HDIM);
    float* ee    = alloc((size_t)SSRC * NBATCH);
    float* ctx   = alloc((size_t)NBATCH * 2 * HDIM);
    float* Xd = Xf;  // alias: encoder input-GEMM buffer reused after enc steps

    float* hf[2] = { st + 0 * HS, st + 4 * HS };
    float* cf[2] = { st + 1 * HS, st + 5 * HS };
    float* hb[2] = { st + 2 * HS, st + 6 * HS };
    float* cb[2] = { st + 3 * HS, st + 7 * HS };
    float* dh[2] = { dst + 0 * HS, dst + 2 * HS };
    float* dc[2] = { dst + 1 * HS, dst + 3 * HS };

    // zero initial LSTM states + output step 0
    hipMemsetAsync(st, 0, (size_t)4 * HS * sizeof(float), stream);
    hipMemsetAsync(out, 0, (size_t)NBATCH * VTGT * sizeof(float), stream);

    // encoder input GEMMs (embedding gather fused): X = emb[source] @ Wih.T + b
    {
        dim3 g(G4H / 128, (SSRC * NBATCH + 127) / 128);
        gemm_bias_kernel<<<g, 256, 0, stream>>>(enc_emb, source, EDIM, enc_Wih_f, EDIM,
                                                enc_b_f, Xf, G4H, SSRC * NBATCH, G4H, EDIM);
        gemm_bias_kernel<<<g, 256, 0, stream>>>(enc_emb, source, EDIM, enc_Wih_b, EDIM,
                                                enc_b_b, Xb, G4H, SSRC * NBATCH, G4H, EDIM);
    }

    // encoder recurrent steps (fwd + bwd fused per launch)
    for (int t = 0; t < SSRC; ++t) {
        LstmSet f, bwd;
        f.X = Xf + (size_t)t * NBATCH * G4H;
        f.A1 = hf[t & 1]; f.W1 = enc_Whh_f; f.K1 = HDIM; f.ldw1 = HDIM;
        f.A2 = nullptr; f.W2 = nullptr; f.K2 = 0; f.ldw2 = 0;
        f.c_in = cf[t & 1]; f.h_out = hf[(t + 1) & 1]; f.c_out = cf[(t + 1) & 1];
        f.h_store = out_f + (size_t)t * HS;

        bwd.X = Xb + (size_t)(SSRC - 1 - t) * NBATCH * G4H;
        bwd.A1 = hb[t & 1]; bwd.W1 = enc_Whh_b; bwd.K1 = HDIM; bwd.ldw1 = HDIM;
        bwd.A2 = nullptr; bwd.W2 = nullptr; bwd.K2 = 0; bwd.ldw2 = 0;
        bwd.c_in = cb[t & 1]; bwd.h_out = hb[(t + 1) & 1]; bwd.c_out = cb[(t + 1) & 1];
        bwd.h_store = out_b + (size_t)(SSRC - 1 - t) * HS;   // pre-reversed
        lstm_step_kernel<<<512, 256, 0, stream>>>(f, bwd);
    }

    // step-invariant attention key term + decoder init state
    // NOTE: fc_hid takes concat(h_final); fc_cell takes concat(C_final) — NOT h!
    ee_kernel<<<SSRC * NBATCH, 64, 0, stream>>>(out_f, out_b, energy_W + HDIM, energy_b, ee);
    hcat_kernel<<<NBATCH, 256, 0, stream>>>(hf[0], hb[0], hcat);
    hcat_kernel<<<NBATCH, 256, 0, stream>>>(cf[0], cb[0], ccat);
    {
        dim3 g(HDIM / 128, 1);
        gemm_bias_kernel<<<g, 256, 0, stream>>>(hcat, nullptr, 2 * HDIM, fc_hid_W, 2 * HDIM,
                                                fc_hid_b, dh[0], HDIM, NBATCH, HDIM, 2 * HDIM);
        gemm_bias_kernel<<<g, 256, 0, stream>>>(ccat, nullptr, 2 * HDIM, fc_cell_W, 2 * HDIM,
                                                fc_cell_b, dc[0], HDIM, NBATCH, HDIM, 2 * HDIM);
    }

    // decoder embedding contribution (reuses Xf buffer)
    {
        dim3 g(G4H / 128, (TSTEPS * NBATCH + 127) / 128);
        gemm_bias_kernel<<<g, 256, 0, stream>>>(dec_emb, target, EDIM, dec_Wih + 2 * HDIM,
                                                2 * HDIM + EDIM, dec_b, Xd, G4H,
                                                TSTEPS * NBATCH, G4H, EDIM);
    }

    // decoder steps
    for (int t = 0; t < TSTEPS; ++t) {
        attn_kernel<<<NBATCH, 256, 0, stream>>>(dh[t & 1], energy_W, ee, out_f, out_b, ctx);
        LstmSet d;
        d.X = Xd + (size_t)t * NBATCH * G4H;
        d.A1 = ctx; d.W1 = dec_Wih; d.K1 = 2 * HDIM; d.ldw1 = 2 * HDIM + EDIM;
        d.A2 = dh[t & 1]; d.W2 = dec_Whh; d.K2 = HDIM; d.ldw2 = HDIM;
        d.c_in = dc[t & 1]; d.h_out = dh[(t + 1) & 1]; d.c_out = dc[(t + 1) & 1];
        d.h_store = Hs + (size_t)t * HS;
        lstm_step_kernel<<<256, 256, 0, stream>>>(d, d);
    }

    // deferred output projection: preds = Hs @ fc_W.T + fc_b  -> out[1:]
    {
        dim3 g((VTGT + 127) / 128, (TSTEPS * NBATCH + 127) / 128);
        gemm_bias_kernel<<<g, 256, 0, stream>>>(Hs, nullptr, HDIM, fc_W, HDIM, fc_b,
                                                out + (size_t)NBATCH * VTGT, VTGT,
                                                TSTEPS * NBATCH, VTGT, HDIM);
    }
}